// Round 1
// baseline (346.947 us; speedup 1.0000x reference)
//
#include <hip/hip_runtime.h>
#include <stdint.h>

typedef __attribute__((ext_vector_type(8))) short short8;
typedef __attribute__((ext_vector_type(8))) unsigned short ushort8;
typedef __attribute__((ext_vector_type(4))) float floatx4;

#define W_DIM 900
#define NPAD  450
#define NT    32           // K tiles: 1024 / BK, BK = 32
#define BUFB  32768        // bytes per LDS buffer: A 16 KB + B 16 KB

// round-half-up fp32 -> bf16 (bias ~2^-17 relative; fine over ~1M-term sums)
__device__ __forceinline__ unsigned short f2bf(float f) {
  unsigned int u = __builtin_bit_cast(unsigned int, f);
  return (unsigned short)((u + 0x8000u) >> 16);
}

__device__ __forceinline__ ushort8 pk8(float4 a, float4 b) {
  ushort8 o;
  o[0] = f2bf(a.x); o[1] = f2bf(a.y); o[2] = f2bf(a.z); o[3] = f2bf(a.w);
  o[4] = f2bf(b.x); o[5] = f2bf(b.y); o[6] = f2bf(b.z); o[7] = f2bf(b.w);
  return o;
}

// Raw barrier: drain LDS ops only. Global loads stay in flight across it
// (this is the whole point -- __syncthreads() would emit vmcnt(0)).
#define BARRIER() do { asm volatile("s_waitcnt lgkmcnt(0)" ::: "memory"); \
                       __builtin_amdgcn_s_barrier(); } while (0)

// ---------------------------------------------------------------------------
// out[b,s] = sum_{i-j-450 = s (mod 900)} <x1_i, x2_j>, D = H*C = 1024.
// One block = one 256x256 gram tile of one batch. 8 waves (2M x 4N), each
// wave computes 128x64 via 8x4 frags of mfma_f32_16x16x32_bf16.
//
// K-pipeline (quad-buffered LDS, 4 x 32 KB, one raw barrier per K-tile):
//   tile t: BARRIER; convert regs(t+1 data)->buf[(t+1)&3]; issue global
//   loads(t+2)->regs; 2 MFMA phases on buf[t&3]. Loads live across 2 barriers;
//   vmcnt is only waited (by the compiler) where the data is converted.
// LDS image: subtile s = row>>4 at s*1024; chunk (r16 = row&15, k8 = k>>3) at
// slot (k8*16 + r16)*16 bytes == reader-lane*16  -> both ds_write and all
// ds_read_b128 are consecutive-lane (conflict-free).
// Grid 256 = 16 tiles * 16 batches, x = tile*16 + b so x%8 = b%8: the two
// batches {c, c+8} share an XCD; the active K-slab set (~0.5 MB) is L2-resident.
// ---------------------------------------------------------------------------
__global__ __launch_bounds__(512, 2)
void fused_gram_band(const float* __restrict__ X1, const float* __restrict__ X2,
                     float* __restrict__ out) {
  const int x  = blockIdx.x;
  const int b  = x & 15;
  const int t4 = x >> 4;
  const int it = t4 >> 2;            // A tile: rows it*256..
  const int jt = t4 & 3;             // B tile: rows jt*256..

  __shared__ __align__(16) unsigned char smem[4 * BUFB];   // 128 KiB

  const int tid  = threadIdx.x;
  const int lane = tid & 63;
  const int warp = tid >> 6;         // 0..7
  const int wm   = warp >> 2;        // 0..1 (M)
  const int wn   = warp & 3;         // 0..3 (N)
  const int r16  = lane & 15;
  const int quad = lane >> 4;

  // ---- staging geometry: thread owns chunks (subtile=warp, slot=lane) and
  // (subtile=warp+8, slot=lane) of both A and B images.
  const int rA0 = it * 256 + warp * 16 + r16;
  const int rA1 = rA0 + 128;
  const int rB0 = jt * 256 + warp * 16 + r16;
  const int rB1 = rB0 + 128;
  const bool okA0 = rA0 < W_DIM, okA1 = rA1 < W_DIM;
  const bool okB0 = rB0 < W_DIM, okB1 = rB1 < W_DIM;

  const size_t bbase = (size_t)b * 4 * W_DIM * 256;
  const int kcol = quad * 8;                      // k8*8 consecutive c
  const float* pA0 = X1 + bbase + (size_t)rA0 * 256 + kcol;
  const float* pA1 = X1 + bbase + (size_t)rA1 * 256 + kcol;
  const float* pB0 = X2 + bbase + (size_t)rB0 * 256 + kcol;
  const float* pB1 = X2 + bbase + (size_t)rB1 * 256 + kcol;

  const float4 fz = make_float4(0.f, 0.f, 0.f, 0.f);
  float4 xa0, xa1, xa2, xa3, xb0, xb1, xb2, xb3;

#define LOADS(kt_)                                                            \
  { const size_t ko = (size_t)((((kt_) >> 3) * (W_DIM * 256)) +               \
                               (((kt_) & 7) * 32));                           \
    xa0 = okA0 ? *(const float4*)(pA0 + ko)     : fz;                         \
    xa1 = okA0 ? *(const float4*)(pA0 + ko + 4) : fz;                         \
    xa2 = okA1 ? *(const float4*)(pA1 + ko)     : fz;                         \
    xa3 = okA1 ? *(const float4*)(pA1 + ko + 4) : fz;                         \
    xb0 = okB0 ? *(const float4*)(pB0 + ko)     : fz;                         \
    xb1 = okB0 ? *(const float4*)(pB0 + ko + 4) : fz;                         \
    xb2 = okB1 ? *(const float4*)(pB1 + ko)     : fz;                         \
    xb3 = okB1 ? *(const float4*)(pB1 + ko + 4) : fz;                         \
  }

#define CVTSTORE(wr_)                                                         \
  { unsigned char* wb = smem + (wr_) * BUFB + (tid << 4);                     \
    *(ushort8*)(wb)         = pk8(xa0, xa1);   /* A subtile warp   */         \
    *(ushort8*)(wb + 8192)  = pk8(xa2, xa3);   /* A subtile warp+8 */         \
    *(ushort8*)(wb + 16384) = pk8(xb0, xb1);   /* B subtile warp   */         \
    *(ushort8*)(wb + 24576) = pk8(xb2, xb3);   /* B subtile warp+8 */         \
  }

  floatx4 acc[8][4];
#pragma unroll
  for (int i = 0; i < 8; ++i)
#pragma unroll
    for (int j = 0; j < 4; ++j) acc[i][j] = (floatx4)0.0f;

  // frag read bases: identity slot addressing, conflict-free
  const unsigned char* aRd = smem + (wm << 13) + (lane << 4);           // A half
  const unsigned char* bRd = smem + 16384 + (wn << 12) + (lane << 4);   // B quarter

  // ---- prologue: stage tile0, issue tile1 loads
  LOADS(0);
  CVTSTORE(0);     // compiler inserts the vmcnt wait for xa/xb here
  LOADS(1);

  for (int t = 0; t < NT; ++t) {
    const int cur = t & 3;
    BARRIER();                                   // buf[cur] written & visible
    if (t < NT - 1) CVTSTORE((t + 1) & 3);       // consume in-flight loads
    if (t < NT - 2) LOADS(t + 2);                // 2-tiles-ahead, spans barriers

    const unsigned char* aP = aRd + cur * BUFB;
    const unsigned char* bP = bRd + cur * BUFB;

    short8 af[4], bf[4];
#pragma unroll
    for (int ni = 0; ni < 4; ++ni) bf[ni] = *(const short8*)(bP + ni * 1024);
#pragma unroll
    for (int mi = 0; mi < 4; ++mi) af[mi] = *(const short8*)(aP + mi * 1024);
    __builtin_amdgcn_s_setprio(1);
#pragma unroll
    for (int mi = 0; mi < 4; ++mi)
#pragma unroll
      for (int ni = 0; ni < 4; ++ni)
        acc[mi][ni] = __builtin_amdgcn_mfma_f32_16x16x32_bf16(
            af[mi], bf[ni], acc[mi][ni], 0, 0, 0);
    __builtin_amdgcn_s_setprio(0);

#pragma unroll
    for (int mi = 0; mi < 4; ++mi)
      af[mi] = *(const short8*)(aP + (mi + 4) * 1024);
    __builtin_amdgcn_s_setprio(1);
#pragma unroll
    for (int mi = 0; mi < 4; ++mi)
#pragma unroll
      for (int ni = 0; ni < 4; ++ni)
        acc[mi + 4][ni] = __builtin_amdgcn_mfma_f32_16x16x32_bf16(
            af[mi], bf[ni], acc[mi + 4][ni], 0, 0, 0);
    __builtin_amdgcn_s_setprio(0);
  }

  // ---- Epilogue: gram[i,j] -> out[b, (i-j-450) mod 900]; 4 passes of 64 rows.
  __syncthreads();
  float* Ep = (float*)smem;                      // [64][260] = 66,560 B
  const int dbase = it * 256 - jt * 256 - NPAD;

  for (int p = 0; p < 4; ++p) {
    if (wm == (p >> 1)) {
      const int mib = (p & 1) * 4;
#pragma unroll
      for (int mo = 0; mo < 4; ++mo)
#pragma unroll
        for (int ni = 0; ni < 4; ++ni)
#pragma unroll
          for (int rr = 0; rr < 4; ++rr) {
            const int lr = mo * 16 + quad * 4 + rr;   // tile row p*64 + lr
            const int c  = wn * 64 + ni * 16 + r16;   // tile col
            Ep[lr * 260 + c] = acc[mib + mo][ni][rr];
          }
    }
    __syncthreads();
    if (tid < 319) {
      const int d = tid - 255;                   // lr - c in [-255, 63]
      int k0 = d > 0 ? d : 0;
      int k1 = 256 + d; if (k1 > 64) k1 = 64;
      float s = 0.0f;
      for (int k = k0; k < k1; ++k) s += Ep[k * 260 + (k - d)];
      int dg = dbase + p * 64 + d;               // in (-1474, 574)
      int sidx = dg % W_DIM;
      if (sidx < 0) sidx += W_DIM;
      atomicAdd(&out[b * W_DIM + sidx], s);
    }
    __syncthreads();
  }
}

extern "C" void kernel_launch(void* const* d_in, const int* in_sizes, int n_in,
                              void* d_out, int out_size, void* d_ws, size_t ws_size,
                              hipStream_t stream) {
  const float* x1 = (const float*)d_in[0];
  const float* x2 = (const float*)d_in[1];
  float* out = (float*)d_out;

  hipMemsetAsync(d_out, 0, (size_t)out_size * sizeof(float), stream);
  fused_gram_band<<<dim3(256), 512, 0, stream>>>(x1, x2, out);
}

// Round 2
// 179.904 us; speedup vs baseline: 1.9285x; 1.9285x over previous
//
#include <hip/hip_runtime.h>
#include <stdint.h>

typedef __attribute__((ext_vector_type(8))) short short8;
typedef __attribute__((ext_vector_type(8))) unsigned short ushort8;
typedef __attribute__((ext_vector_type(4))) float floatx4;

#define W_DIM 900
#define NPAD  450
#define TM    256
#define TN    128
#define BK    32
#define LDST  40          // LDS row stride (elems): 32 + 8 pad -> 80 B, 16B-aligned rows,
                          // bank pattern 2-way max (free per m136)

__device__ __forceinline__ unsigned short f2bf(float f) {
  // round-half-up: bias ~2^-17 relative, negligible over 921600-term sums
  unsigned int u = __builtin_bit_cast(unsigned int, f);
  return (unsigned short)((u + 0x8000u) >> 16);
}

// ---------------------------------------------------------------------------
// Fused: fp32 inputs -> bf16 staged tiles -> gram GEMM -> circular-band reduce.
// out[b,s] = sum_{i-j-450 = s (mod 900)} <x1_i, x2_j>  (D = H*C = 1024)
//
// Tile 256x128, BK=32, K SPLIT BY 2 (each block does 16 of 32 k-tiles; the
// epilogue's atomicAdd merges the two partial gram sums). Grid: 1024 blocks =
// 2 ks * 8 jt * 4 it * 16 b, x low bits = b so x%8 = b%8 -> all blocks of one
// batch share an XCD (L2 tile reuse). 4 blocks/CU resident (LDS 4x33.8KB).
// 4 waves; wave (wm,wn) computes 128x64 via 8x4 frags of mfma 16x16x32_bf16.
// Pipeline: global loads for kt+1 issued before MFMA(kt) -> in flight across
// the barrier; ds_writes wait on them at the top of kt+1.
// ---------------------------------------------------------------------------
__global__ __launch_bounds__(256, 2)
void fused_gram_band(const float* __restrict__ X1, const float* __restrict__ X2,
                     float* __restrict__ out) {
  const int x  = blockIdx.x;
  const int b  = x & 15;
  const int it = (x >> 4) & 3;         // A tile: rows it*256..
  const int jt = (x >> 6) & 7;         // B tile: rows jt*128..
  const int ks = x >> 9;               // K half: kt in [ks*16, ks*16+16)

  __shared__ __align__(16) unsigned char smem[64 * 132 * 4];  // 33792 B
  unsigned short* As = (unsigned short*)smem;                 // [256][LDST]
  unsigned short* Bs = As + TM * LDST;                        // [128][LDST]
  // staging = 384*40*2 = 30720 B <= 33792 (epilogue Ep aliases all of it)

  const int tid  = threadIdx.x;
  const int lane = tid & 63;
  const int warp = tid >> 6;
  const int wm   = warp >> 1;
  const int wn   = warp & 1;

  // ---- staging map: lane -> (row sub = lane>>2, 8-elem chunk c8 = (lane&3)*8)
  // one step stages 16 rows x 32 k-elems; A: 4 steps (64 rows/wave), B: 2.
  const int rsub = lane >> 2;
  const int c8   = (lane & 3) << 3;

  int arow[4], brow[2];
  bool aok[4], bok[2];
#pragma unroll
  for (int s = 0; s < 4; ++s) {
    arow[s] = it * TM + warp * 64 + s * 16 + rsub;
    aok[s]  = arow[s] < W_DIM;         // padded rows (>=900) stay zero
  }
#pragma unroll
  for (int s = 0; s < 2; ++s) {
    brow[s] = jt * TN + warp * 32 + s * 16 + rsub;
    bok[s]  = brow[s] < W_DIM;
  }

  const size_t bbase = (size_t)b * 4 * W_DIM * 256;

  float4 va[4][2], vb[2][2];
  const float4 fz = make_float4(0.f, 0.f, 0.f, 0.f);

#define LOAD_SLAB(kt)                                                          \
  {                                                                            \
    const size_t koff = bbase + (size_t)((kt) >> 3) * (W_DIM * 256) +          \
                        ((kt) & 7) * 32 + c8;                                  \
    _Pragma("unroll")                                                          \
    for (int s = 0; s < 4; ++s) {                                              \
      va[s][0] = fz; va[s][1] = fz;                                            \
      if (aok[s]) {                                                            \
        const float* p = X1 + koff + (size_t)arow[s] * 256;                    \
        va[s][0] = *(const float4*)p;                                          \
        va[s][1] = *(const float4*)(p + 4);                                    \
      }                                                                        \
    }                                                                          \
    _Pragma("unroll")                                                          \
    for (int s = 0; s < 2; ++s) {                                              \
      vb[s][0] = fz; vb[s][1] = fz;                                            \
      if (bok[s]) {                                                            \
        const float* p = X2 + koff + (size_t)brow[s] * 256;                    \
        vb[s][0] = *(const float4*)p;                                          \
        vb[s][1] = *(const float4*)(p + 4);                                    \
      }                                                                        \
    }                                                                          \
  }

  floatx4 acc[8][4];
#pragma unroll
  for (int i = 0; i < 8; ++i)
#pragma unroll
    for (int j = 0; j < 4; ++j) acc[i][j] = (floatx4)0.0f;

  const int quad = lane >> 4;
  const int r16  = lane & 15;
  const unsigned short* ArowBase = As + (wm * 128 + r16) * LDST + quad * 8;
  const unsigned short* BrowBase = Bs + (wn * 64 + r16) * LDST + quad * 8;

  const int k0 = ks << 4;              // this block's K range: [k0, k0+16)

  LOAD_SLAB(k0);

  for (int kt = k0; kt < k0 + 16; ++kt) {
    __syncthreads();                   // frag reads of kt-1 done before overwrite
    // convert + write slab kt (compiler inserts vmcnt wait on va/vb here)
#pragma unroll
    for (int s = 0; s < 4; ++s) {
      ushort8 o;
      o[0] = f2bf(va[s][0].x); o[1] = f2bf(va[s][0].y);
      o[2] = f2bf(va[s][0].z); o[3] = f2bf(va[s][0].w);
      o[4] = f2bf(va[s][1].x); o[5] = f2bf(va[s][1].y);
      o[6] = f2bf(va[s][1].z); o[7] = f2bf(va[s][1].w);
      *(ushort8*)&As[(warp * 64 + s * 16 + rsub) * LDST + c8] = o;
    }
#pragma unroll
    for (int s = 0; s < 2; ++s) {
      ushort8 o;
      o[0] = f2bf(vb[s][0].x); o[1] = f2bf(vb[s][0].y);
      o[2] = f2bf(vb[s][0].z); o[3] = f2bf(vb[s][0].w);
      o[4] = f2bf(vb[s][1].x); o[5] = f2bf(vb[s][1].y);
      o[6] = f2bf(vb[s][1].z); o[7] = f2bf(vb[s][1].w);
      *(ushort8*)&Bs[(warp * 32 + s * 16 + rsub) * LDST + c8] = o;
    }
    __syncthreads();                   // writes visible

    if (kt < k0 + 15) LOAD_SLAB(kt + 1);  // in flight across MFMA + next barrier

    short8 af[8], bf[4];
#pragma unroll
    for (int mi = 0; mi < 8; ++mi)
      af[mi] = *(const short8*)(ArowBase + mi * 16 * LDST);
#pragma unroll
    for (int ni = 0; ni < 4; ++ni)
      bf[ni] = *(const short8*)(BrowBase + ni * 16 * LDST);
#pragma unroll
    for (int mi = 0; mi < 8; ++mi)
#pragma unroll
      for (int ni = 0; ni < 4; ++ni)
        acc[mi][ni] = __builtin_amdgcn_mfma_f32_16x16x32_bf16(
            af[mi], bf[ni], acc[mi][ni], 0, 0, 0);
  }

  // ---- Epilogue: gram[i,j] -> out[b, (i-j-450) mod 900]; 4 passes of 64 rows.
  __syncthreads();
  float* Ep = (float*)smem;            // [64][132]
  const int dbase = it * TM - jt * TN - NPAD;

  for (int p = 0; p < 4; ++p) {
    if (wm == (p >> 1)) {
      const int mib = (p & 1) * 4;
#pragma unroll
      for (int mo = 0; mo < 4; ++mo)
#pragma unroll
        for (int ni = 0; ni < 4; ++ni)
#pragma unroll
          for (int rr = 0; rr < 4; ++rr) {
            const int lr = mo * 16 + quad * 4 + rr;       // tile row p*64 + lr
            const int c  = wn * 64 + ni * 16 + r16;       // tile col
            Ep[lr * 132 + c] = acc[mib + mo][ni][rr];
          }
    }
    __syncthreads();
    if (tid < 191) {
      const int d = tid - 127;         // lr - c in [-127, 63]
      int k0e = d > 0 ? d : 0;
      int k1e = 128 + d; if (k1e > 64) k1e = 64;
      float s = 0.0f;
      for (int k = k0e; k < k1e; ++k) s += Ep[k * 132 + (k - d)];
      int dg = dbase + p * 64 + d;     // in (-1800, 1800)
      int sidx = dg % W_DIM;
      if (sidx < 0) sidx += W_DIM;
      atomicAdd(&out[b * W_DIM + sidx], s);
    }
    __syncthreads();
  }
}

extern "C" void kernel_launch(void* const* d_in, const int* in_sizes, int n_in,
                              void* d_out, int out_size, void* d_ws, size_t ws_size,
                              hipStream_t stream) {
  const float* x1 = (const float*)d_in[0];
  const float* x2 = (const float*)d_in[1];
  float* out = (float*)d_out;

  hipMemsetAsync(d_out, 0, (size_t)out_size * sizeof(float), stream);
  fused_gram_band<<<dim3(1024), 256, 0, stream>>>(x1, x2, out);
}